// Round 3
// baseline (158.423 us; speedup 1.0000x reference)
//
#include <hip/hip_runtime.h>

// VQ-VAE VectorQuantizer forward, MI355X (gfx950), fp32.
// N=32768 points x D=64 dims, K=1024 codes.
// Out: [0]=loss, [1..QE]=quantized [B,D,H,W], [+..]=indices [B,H*W] as f32.
//
// R7: x-operand off all memory pipes. R5 was LDS-return-bound (12288
// wave-b128 ~147K cyc/CU); R6 moved x to global VMEM and exposed L2 latency
// (VALU busy-cycles identical, stalls worse). Now: x per (wave,d) is 8
// wave-uniform floats -> hold x in per-lane VGPRs (lane <-> d, D=64=wave
// size, loaded ONCE from global) and broadcast per d via v_readlane
// (SGPR result = legal scalar src of v_fma). Steady-state per thread-d:
// 2 ds_read_b128 (e only) + 8 readlane + 64 fmaf.
// Pipe model/CU: LDS 4096 wave-b128 ~49K cyc; VALU ~80K cyc (binding).
// e in LDS with [d][h][g][q] swizzled rows (lane-contiguous 16B reads,
// conflict-free, verified R6). 2 chunks x 512 codes.
// All per-(point,code) fmaf chains, fold exprs, tie-breaks, and the loss
// partition/order are verbatim R6 (passed, absmax 0) -> absmax must stay 0.

constexpr int D_   = 64;
constexpr int HW   = 1024;     // H*W
constexpr int K_   = 1024;
constexpr int PTS  = 128;      // points per block
constexpr int CK   = 512;      // codes per chunk (2 chunks)
constexpr int SEC  = 520;      // eTs row stride (floats), 16B-aligned rows
constexpr int QE   = 2097152;
constexpr int IDX_OFF = 1 + QE;

__device__ __forceinline__ float bcast_lane(float v, int l) {
  return __int_as_float(__builtin_amdgcn_readlane(__float_as_int(v), l));
}

__global__ __launch_bounds__(1024, 4) void vq_main_kernel(
    const float* __restrict__ in, const float* __restrict__ emb,
    float* __restrict__ out, float* __restrict__ loss_acc,
    unsigned* __restrict__ cnt) {
  __shared__ float eTs[D_ * SEC];    // 133.1 KB; row d = [h][g][q] swizzle
  __shared__ float e2s[K_];          // 4 KB
  __shared__ float x2s[PTS];
  __shared__ int   idx_sel[PTS];
  __shared__ float redbuf[8];

  const int t    = threadIdx.x;
  const int lane = t & 63;           // K-loop role: code group AND d-slot
  const int wv   = t >> 6;           // wave 0..15 = point group: 8 points
  const int p0   = wv * 8;
  const int blk  = blockIdx.x;
  const int b    = blk >> 3;         // 8 blocks per image
  const int hw0  = (blk & 7) * PTS;
  const float* inb = in + b * (D_ * HW) + hw0;

  // staging role: chunk-local code kl, dim-half h2 (32 dims)
  const int kl = t & 511;
  const int h2 = t >> 9;
  // swizzled position of code kl within a d-row: [h][g][q]
  const int pos = ((kl >> 2) & 1) * 256 + (kl >> 3) * 4 + (kl & 3);

  // ---- e2s: 1 code/thread, body identical to R4/R5/R6 (rounding!) ----
  {
    const float4* e4 = (const float4*)(emb + t * 64);
    float s = 0.f;
#pragma unroll
    for (int q = 0; q < 16; ++q) {
      float4 v = e4[q];
      s += v.x * v.x; s += v.y * v.y; s += v.z * v.z; s += v.w * v.w;
    }
    e2s[t] = s;
  }

  // ---- stage chunk 0 into swizzled eTs ----
  {
    const float4* g = (const float4*)(emb + kl * 64 + h2 * 32);
    float4 pf[8];
#pragma unroll
    for (int r = 0; r < 8; ++r) pf[r] = g[r];
#pragma unroll
    for (int r = 0; r < 8; ++r) {
      int d = h2 * 32 + r * 4;
      eTs[(d + 0) * SEC + pos] = pf[r].x;
      eTs[(d + 1) * SEC + pos] = pf[r].y;
      eTs[(d + 2) * SEC + pos] = pf[r].z;
      eTs[(d + 3) * SEC + pos] = pf[r].w;
    }
  }

  // ---- x into per-lane registers: lane d holds x[p0..p0+7][d] ----
  // one-time 32B load per lane (4KB-strided gather, L2-hot, off critical path)
  float4 xr0, xr1;
  {
    const float* xrow = inb + lane * HW + p0;
    xr0 = *(const float4*)(xrow);
    xr1 = *(const float4*)(xrow + 4);
  }

  // ---- x2[p] from global (sequential d fmaf chain — identical values) ----
  if (t < PTS) {
    float s = 0.f;
#pragma unroll 8
    for (int d = 0; d < D_; ++d) { float xv = inb[d * HW + t]; s = fmaf(xv, xv, s); }
    x2s[t] = s;
  }
  __syncthreads();

  float x2v[8];
  {
    float4 xa = *(const float4*)&x2s[p0];      // broadcast read
    float4 xb = *(const float4*)&x2s[p0 + 4];
    x2v[0]=xa.x; x2v[1]=xa.y; x2v[2]=xa.z; x2v[3]=xa.w;
    x2v[4]=xb.x; x2v[5]=xb.y; x2v[6]=xb.z; x2v[7]=xb.w;
  }

  float minv[8]; int mini[8];
#pragma unroll
  for (int i = 0; i < 8; ++i) { minv[i] = 3.4e38f; mini[i] = 0; }

  // ---- K loop: 2 chunks of 512 codes ----
#pragma unroll 1
  for (int c = 0; c < 2; ++c) {
    float acc[8][8];
#pragma unroll
    for (int i = 0; i < 8; ++i)
#pragma unroll
      for (int j = 0; j < 8; ++j) acc[i][j] = 0.f;

    const float* ep = &eTs[lane * 4];    // lane-contiguous 16B: conflict-free
#pragma unroll 8
    for (int d = 0; d < D_; ++d) {
      float4 e0 = *(const float4*)(ep);          // codes lane*8+0..3
      float4 e1 = *(const float4*)(ep + 256);    // codes lane*8+4..7
      ep += SEC;
      // broadcast this d's 8 x-values from lane d (exact bits)
      float xs[8];
      xs[0] = bcast_lane(xr0.x, d); xs[1] = bcast_lane(xr0.y, d);
      xs[2] = bcast_lane(xr0.z, d); xs[3] = bcast_lane(xr0.w, d);
      xs[4] = bcast_lane(xr1.x, d); xs[5] = bcast_lane(xr1.y, d);
      xs[6] = bcast_lane(xr1.z, d); xs[7] = bcast_lane(xr1.w, d);
      float ef[8] = {e0.x, e0.y, e0.z, e0.w, e1.x, e1.y, e1.z, e1.w};
#pragma unroll
      for (int i = 0; i < 8; ++i)
#pragma unroll
        for (int j = 0; j < 8; ++j)
          acc[i][j] = fmaf(xs[i], ef[j], acc[i][j]);
    }

    // fold: u = fl(fl(x2 - 2*dot) + e2) — identical expression/order
    float e2f[8];
    {
      const float4* p4 = (const float4*)&e2s[c * CK + lane * 8];
      float4 v0 = p4[0], v1 = p4[1];
      e2f[0]=v0.x; e2f[1]=v0.y; e2f[2]=v0.z; e2f[3]=v0.w;
      e2f[4]=v1.x; e2f[5]=v1.y; e2f[6]=v1.z; e2f[7]=v1.w;
    }
#pragma unroll
    for (int j = 0; j < 8; ++j) {
      int cg = c * CK + lane * 8 + j;            // ascending within thread
      float e2v = e2f[j];
#pragma unroll
      for (int i = 0; i < 8; ++i) {
        float u = fmaf(-2.f, acc[i][j], x2v[i]) + e2v;
        if (u < minv[i]) { minv[i] = u; mini[i] = cg; }
      }
    }

    // stage chunk 1 (exposed ~1us once; keeps VGPR under the 128 cap)
    if (c == 0) {
      __syncthreads();   // all waves done reading eTs chunk 0
      const float4* g = (const float4*)(emb + (CK + kl) * 64 + h2 * 32);
      float4 pf[8];
#pragma unroll
      for (int r = 0; r < 8; ++r) pf[r] = g[r];
#pragma unroll
      for (int r = 0; r < 8; ++r) {
        int d = h2 * 32 + r * 4;
        eTs[(d + 0) * SEC + pos] = pf[r].x;
        eTs[(d + 1) * SEC + pos] = pf[r].y;
        eTs[(d + 2) * SEC + pos] = pf[r].z;
        eTs[(d + 3) * SEC + pos] = pf[r].w;
      }
      __syncthreads();
    }
  }

  // ---- argmin: full-wave butterfly (each wave owns its 8 points) ----
#pragma unroll
  for (int i = 0; i < 8; ++i) {
    float v = minv[i]; int ix = mini[i];
#pragma unroll
    for (int off = 1; off < 64; off <<= 1) {
      float vo = __shfl_xor(v, off);
      int   io = __shfl_xor(ix, off);
      if (vo < v || (vo == v && io < ix)) { v = vo; ix = io; }  // tie -> lower
    }
    if (lane == 0) idx_sel[p0 + i] = ix;
  }
  __syncthreads();

  if (t < PTS) out[IDX_OFF + blk * PTS + t] = (float)idx_sel[t];

  // ---- fused epilogue: gather codes, loss partial, store quantized ----
  // t<512 with R4's EXACT per-thread partition/order -> loss bits identical.
  float* outq = out + 1 + b * (D_ * HW) + hw0;
  float lp = 0.f;
  if (t < 512) {
#pragma unroll
    for (int i = 0; i < 4; ++i) {
      int fi = t + i * 512;               // 0..2047
      int p = fi & 127, qd = fi >> 7;     // p contiguous per wave
      int cidx = idx_sel[p];
      float4 q = *(const float4*)(emb + cidx * 64 + qd * 4);
      float xv0 = inb[(qd * 4 + 0) * HW + p];
      float xv1 = inb[(qd * 4 + 1) * HW + p];
      float xv2 = inb[(qd * 4 + 2) * HW + p];
      float xv3 = inb[(qd * 4 + 3) * HW + p];
      float d0 = q.x - xv0, d1 = q.y - xv1, d2 = q.z - xv2, d3 = q.w - xv3;
      lp = fmaf(d0, d0, lp); lp = fmaf(d1, d1, lp);
      lp = fmaf(d2, d2, lp); lp = fmaf(d3, d3, lp);
      outq[(qd * 4 + 0) * HW + p] = xv0 + d0;
      outq[(qd * 4 + 1) * HW + p] = xv1 + d1;
      outq[(qd * 4 + 2) * HW + p] = xv2 + d2;
      outq[(qd * 4 + 3) * HW + p] = xv3 + d3;
    }

    // loss: wave -> block partials in R4's exact order (waves 0..7)
#pragma unroll
    for (int off = 1; off < 64; off <<= 1) lp += __shfl_xor(lp, off);
    if ((t & 63) == 0) redbuf[t >> 6] = lp;
  }
  __syncthreads();
  if (t == 0) {
    float part = 0.f;
#pragma unroll
    for (int w = 0; w < 8; ++w) part += redbuf[w];
    atomicAdd(loss_acc, part);
    __threadfence();
    unsigned old = atomicAdd(cnt, 1u);
    if (old == 255u) {
      __threadfence();
      float total = atomicAdd(loss_acc, 0.0f);  // coherent read-back
      float m = total * (1.0f / 2097152.0f);
      out[0] = m + 0.25f * m;                   // ref op order
    }
  }
}

extern "C" void kernel_launch(void* const* d_in, const int* in_sizes, int n_in,
                              void* d_out, int out_size, void* d_ws, size_t ws_size,
                              hipStream_t stream) {
  const float* in  = (const float*)d_in[0];
  const float* emb = (const float*)d_in[1];
  float* out = (float*)d_out;
  float* loss_acc = (float*)d_ws;                 // ws[0]
  unsigned* cnt   = (unsigned*)d_ws + 4;          // ws[4]

  hipMemsetAsync(d_ws, 0, 64, stream);            // zero accumulator + counter
  vq_main_kernel<<<256, 1024, 0, stream>>>(in, emb, out, loss_acc, cnt);
}

// Round 4
// 154.121 us; speedup vs baseline: 1.0279x; 1.0279x over previous
//
#include <hip/hip_runtime.h>

// VQ-VAE VectorQuantizer forward, MI355X (gfx950), fp32.
// N=32768 points x D=64 dims, K=1024 codes.
// Out: [0]=loss, [1..QE]=quantized [B,D,H,W], [+..]=indices [B,H*W] as f32.
//
// R8: 8x8 tile with BOTH operands in LDS at 1024 thr (4 waves/SIMD).
// History: R5 (4x8, 3 LDS/32FMA) = 86.6us, LDS-issue-bound (12288 wave-b128);
// R6 (8x8, x global per-d) exposed L2 latency; R7 (readlane) +26K VALU cyc.
// Fix: 8x8 needs eTs for 512 codes -- too big at 64 d rows (128KB+xT>160KB),
// so stage e in 512-code x 32-dim HALVES (64KB): 4 stages (c,dh), acc runs
// d-ascending 0..63 across halves (bit-identical chain). LDS instrs/CU:
// 16w x 4 b128 x 128 d-steps = 8192 (-33% vs R5), 2 of 4 are wave-uniform
// x broadcasts. Reg-prefetch (16 VGPR) hides stage loads; 3 write-barriers.
// eTs rows: [h][g][q] swizzle (R6-verified conflict-free lane-contiguous
// reads, 2-way writes). xT [d][p] SP=132 as R4/R5.
// All per-(point,code) fmaf chains, fold exprs, tie-breaks, and the loss
// partition/order verbatim passed kernels -> absmax must stay 0.

constexpr int D_   = 64;
constexpr int HW   = 1024;     // H*W
constexpr int K_   = 1024;
constexpr int PTS  = 128;      // points per block
constexpr int CK   = 512;      // codes per chunk (2 chunks)
constexpr int DH   = 32;       // dims per stage half
constexpr int SP   = 132;      // xT row stride (floats)
constexpr int QE   = 2097152;
constexpr int IDX_OFF = 1 + QE;

__global__ __launch_bounds__(1024, 4) void vq_main_kernel(
    const float* __restrict__ in, const float* __restrict__ emb,
    float* __restrict__ out, float* __restrict__ loss_acc,
    unsigned* __restrict__ cnt) {
  __shared__ float eTs[DH * CK];     // 64 KB; row d' = [h][g][q] swizzle
  __shared__ float xT[D_ * SP];      // 33.8 KB, [d][p]
  __shared__ float e2s[K_];          // 4 KB
  __shared__ float x2s[PTS];
  __shared__ int   idx_sel[PTS];
  __shared__ float redbuf[8];

  const int t    = threadIdx.x;
  const int lane = t & 63;           // code group: 8 codes
  const int wv   = t >> 6;           // wave 0..15 = point group: 8 points
  const int p0   = wv * 8;
  const int blk  = blockIdx.x;
  const int b    = blk >> 3;         // 8 blocks per image
  const int hw0  = (blk & 7) * PTS;
  const float* inb = in + b * (D_ * HW) + hw0;

  // staging role: chunk-local code kl, dim-16-group h within the 32-d half
  const int kl = t & 511;
  const int h  = t >> 9;             // 0/1 (wave-uniform)
  // swizzled column of code kl: codes 8L+j -> col (j<4 ? L*4+j : 256+L*4+j-4)
  const int pos = ((kl >> 2) & 1) * 256 + (kl >> 3) * 4 + (kl & 3);

  // ---- stage x tile -> xT[d][p] (coalesced float4) ----
#pragma unroll
  for (int i = 0; i < 2; ++i) {
    int fi = t + i * 1024;                // 0..2047
    int d  = fi >> 5, p4 = fi & 31;
    *(float4*)(&xT[d * SP + p4 * 4]) = *(const float4*)(inb + d * HW + p4 * 4);
  }

  // ---- e2s: 1 code/thread, body identical to R4..R7 (rounding!) ----
  {
    const float4* e4 = (const float4*)(emb + t * 64);
    float s = 0.f;
#pragma unroll
    for (int q = 0; q < 16; ++q) {
      float4 v = e4[q];
      s += v.x * v.x; s += v.y * v.y; s += v.z * v.z; s += v.w * v.w;
    }
    e2s[t] = s;
  }

  // ---- stage (c=0, dh=0) into eTs ----
  {
    const float4* g = (const float4*)(emb + kl * 64 + h * 16);
    float4 pf[4];
#pragma unroll
    for (int r = 0; r < 4; ++r) pf[r] = g[r];
#pragma unroll
    for (int r = 0; r < 4; ++r) {
      int dq = h * 16 + r * 4;
      eTs[(dq + 0) * CK + pos] = pf[r].x;
      eTs[(dq + 1) * CK + pos] = pf[r].y;
      eTs[(dq + 2) * CK + pos] = pf[r].z;
      eTs[(dq + 3) * CK + pos] = pf[r].w;
    }
  }
  __syncthreads();

  // ---- x2[p] from xT (sequential d fmaf chain — identical values) ----
  if (t < PTS) {
    float s = 0.f;
#pragma unroll 8
    for (int d = 0; d < D_; ++d) { float xv = xT[d * SP + t]; s = fmaf(xv, xv, s); }
    x2s[t] = s;
  }
  __syncthreads();

  float minv[8]; int mini[8];
#pragma unroll
  for (int i = 0; i < 8; ++i) { minv[i] = 3.4e38f; mini[i] = 0; }

  // ---- K loop: 2 chunks of 512 codes, each in two 32-d stages ----
#pragma unroll 1
  for (int c = 0; c < 2; ++c) {
    float acc[8][8];
#pragma unroll
    for (int i = 0; i < 8; ++i)
#pragma unroll
      for (int j = 0; j < 8; ++j) acc[i][j] = 0.f;

#pragma unroll 1
    for (int dh = 0; dh < 2; ++dh) {
      const int s = c * 2 + dh;
      // prefetch next stage into regs (hidden under the 32-d compute)
      float4 pf[4];
      if (s < 3) {
        const int cn = (s + 1) >> 1, dn = (s + 1) & 1;
        const float4* g =
            (const float4*)(emb + (cn * CK + kl) * 64 + dn * DH + h * 16);
#pragma unroll
        for (int r = 0; r < 4; ++r) pf[r] = g[r];
      }

      const float* ep = &eTs[lane * 4];          // lane-contiguous: conflict-free
      const float* xp = &xT[dh * DH * SP + p0];  // wave-uniform broadcast
#pragma unroll 8
      for (int dd = 0; dd < DH; ++dd) {
        float4 e0 = *(const float4*)(ep);          // codes lane*8+0..3
        float4 e1 = *(const float4*)(ep + 256);    // codes lane*8+4..7
        float4 xa = *(const float4*)(xp);
        float4 xb = *(const float4*)(xp + 4);
        ep += CK; xp += SP;
        float xf[8] = {xa.x, xa.y, xa.z, xa.w, xb.x, xb.y, xb.z, xb.w};
        float ef[8] = {e0.x, e0.y, e0.z, e0.w, e1.x, e1.y, e1.z, e1.w};
#pragma unroll
        for (int i = 0; i < 8; ++i)
#pragma unroll
          for (int j = 0; j < 8; ++j)
            acc[i][j] = fmaf(xf[i], ef[j], acc[i][j]);
      }

      if (s < 3) {
        __syncthreads();   // all waves done reading this eTs stage
#pragma unroll
        for (int r = 0; r < 4; ++r) {
          int dq = h * 16 + r * 4;
          eTs[(dq + 0) * CK + pos] = pf[r].x;
          eTs[(dq + 1) * CK + pos] = pf[r].y;
          eTs[(dq + 2) * CK + pos] = pf[r].z;
          eTs[(dq + 3) * CK + pos] = pf[r].w;
        }
        __syncthreads();
      }
    }

    // fold: u = fl(fl(x2 - 2*dot) + e2) — identical expression/order
    float x2v[8];
    {
      float4 xa = *(const float4*)&x2s[p0];      // broadcast
      float4 xb = *(const float4*)&x2s[p0 + 4];
      x2v[0]=xa.x; x2v[1]=xa.y; x2v[2]=xa.z; x2v[3]=xa.w;
      x2v[4]=xb.x; x2v[5]=xb.y; x2v[6]=xb.z; x2v[7]=xb.w;
    }
    float e2f[8];
    {
      const float4* p4 = (const float4*)&e2s[c * CK + lane * 8];
      float4 v0 = p4[0], v1 = p4[1];
      e2f[0]=v0.x; e2f[1]=v0.y; e2f[2]=v0.z; e2f[3]=v0.w;
      e2f[4]=v1.x; e2f[5]=v1.y; e2f[6]=v1.z; e2f[7]=v1.w;
    }
#pragma unroll
    for (int j = 0; j < 8; ++j) {
      int cg = c * CK + lane * 8 + j;            // ascending within thread
      float e2v = e2f[j];
#pragma unroll
      for (int i = 0; i < 8; ++i) {
        float u = fmaf(-2.f, acc[i][j], x2v[i]) + e2v;
        if (u < minv[i]) { minv[i] = u; mini[i] = cg; }
      }
    }
  }

  // ---- argmin: full-wave butterfly (each wave owns its 8 points) ----
#pragma unroll
  for (int i = 0; i < 8; ++i) {
    float v = minv[i]; int ix = mini[i];
#pragma unroll
    for (int off = 1; off < 64; off <<= 1) {
      float vo = __shfl_xor(v, off);
      int   io = __shfl_xor(ix, off);
      if (vo < v || (vo == v && io < ix)) { v = vo; ix = io; }  // tie -> lower
    }
    if (lane == 0) idx_sel[p0 + i] = ix;
  }
  __syncthreads();

  if (t < PTS) out[IDX_OFF + blk * PTS + t] = (float)idx_sel[t];

  // ---- fused epilogue: gather codes, loss partial, store quantized ----
  // t<512 with R4's EXACT per-thread partition/order -> loss bits identical.
  // x read from xT (bitwise copy of inb) -> same values as global reads.
  float* outq = out + 1 + b * (D_ * HW) + hw0;
  float lp = 0.f;
  if (t < 512) {
#pragma unroll
    for (int i = 0; i < 4; ++i) {
      int fi = t + i * 512;               // 0..2047
      int p = fi & 127, qd = fi >> 7;     // p contiguous per wave
      int cidx = idx_sel[p];
      float4 q = *(const float4*)(emb + cidx * 64 + qd * 4);
      float xv0 = xT[(qd * 4 + 0) * SP + p];
      float xv1 = xT[(qd * 4 + 1) * SP + p];
      float xv2 = xT[(qd * 4 + 2) * SP + p];
      float xv3 = xT[(qd * 4 + 3) * SP + p];
      float d0 = q.x - xv0, d1 = q.y - xv1, d2 = q.z - xv2, d3 = q.w - xv3;
      lp = fmaf(d0, d0, lp); lp = fmaf(d1, d1, lp);
      lp = fmaf(d2, d2, lp); lp = fmaf(d3, d3, lp);
      outq[(qd * 4 + 0) * HW + p] = xv0 + d0;
      outq[(qd * 4 + 1) * HW + p] = xv1 + d1;
      outq[(qd * 4 + 2) * HW + p] = xv2 + d2;
      outq[(qd * 4 + 3) * HW + p] = xv3 + d3;
    }

    // loss: wave -> block partials in R4's exact order (waves 0..7)
#pragma unroll
    for (int off = 1; off < 64; off <<= 1) lp += __shfl_xor(lp, off);
    if ((t & 63) == 0) redbuf[t >> 6] = lp;
  }
  __syncthreads();
  if (t == 0) {
    float part = 0.f;
#pragma unroll
    for (int w = 0; w < 8; ++w) part += redbuf[w];
    atomicAdd(loss_acc, part);
    __threadfence();
    unsigned old = atomicAdd(cnt, 1u);
    if (old == 255u) {
      __threadfence();
      float total = atomicAdd(loss_acc, 0.0f);  // coherent read-back
      float m = total * (1.0f / 2097152.0f);
      out[0] = m + 0.25f * m;                   // ref op order
    }
  }
}

extern "C" void kernel_launch(void* const* d_in, const int* in_sizes, int n_in,
                              void* d_out, int out_size, void* d_ws, size_t ws_size,
                              hipStream_t stream) {
  const float* in  = (const float*)d_in[0];
  const float* emb = (const float*)d_in[1];
  float* out = (float*)d_out;
  float* loss_acc = (float*)d_ws;                 // ws[0]
  unsigned* cnt   = (unsigned*)d_ws + 4;          // ws[4]

  hipMemsetAsync(d_ws, 0, 64, stream);            // zero accumulator + counter
  vq_main_kernel<<<256, 1024, 0, stream>>>(in, emb, out, loss_acc, cnt);
}

// Round 5
// 138.149 us; speedup vs baseline: 1.1468x; 1.1156x over previous
//
#include <hip/hip_runtime.h>

// VQ-VAE VectorQuantizer forward, MI355X (gfx950), fp32.
// N=32768 points x D=64 dims, K=1024 codes.
// Out: [0]=loss, [1..QE]=quantized [B,D,H,W], [+..]=indices [B,H*W] as f32.
//
// R9: R8 minus the register-pressure bugs. R8's counters showed scratch
// spill (WRITE_SIZE 82MB vs 9MB output, FETCH 25MB vs 5.2MB): pf[4] live
// across the 32-dd compute + unroll-8 load batching exceeded the 128-VGPR
// cap that 1024thr/4-waves-per-SIMD imposes, and acc[8][8] went to scratch.
// Fix: NO reg-prefetch (stage loads between the two barriers; ~700cyc x3
// exposed = ~1us, trivial) and unroll 2 (8 load regs in flight, like the
// spill-free R6). Structure otherwise identical to R8: 8x8 tile, both
// operands in LDS, e staged as 512-code x 32-dim halves (64KB), acc runs
// d-ascending 0..63 across halves (bit-identical chain).
// Pipe model/CU/dd-round: LDS 64 b128 x 12 = 768 cyc vs VALU 512 -> LDS-
// bound, 128 rounds ~= 41us + staging/epilogue.
// All per-(point,code) fmaf chains, fold exprs, tie-breaks, and the loss
// partition/order verbatim passed kernels -> absmax must stay 0.

constexpr int D_   = 64;
constexpr int HW   = 1024;     // H*W
constexpr int K_   = 1024;
constexpr int PTS  = 128;      // points per block
constexpr int CK   = 512;      // codes per chunk (2 chunks)
constexpr int DH   = 32;       // dims per stage half
constexpr int SP   = 132;      // xT row stride (floats)
constexpr int QE   = 2097152;
constexpr int IDX_OFF = 1 + QE;

__global__ __launch_bounds__(1024, 4) void vq_main_kernel(
    const float* __restrict__ in, const float* __restrict__ emb,
    float* __restrict__ out, float* __restrict__ loss_acc,
    unsigned* __restrict__ cnt) {
  __shared__ float eTs[DH * CK];     // 64 KB; row d' = [h][g][q] swizzle
  __shared__ float xT[D_ * SP];      // 33.8 KB, [d][p]
  __shared__ float e2s[K_];          // 4 KB
  __shared__ float x2s[PTS];
  __shared__ int   idx_sel[PTS];
  __shared__ float redbuf[8];

  const int t    = threadIdx.x;
  const int lane = t & 63;           // code group: 8 codes
  const int wv   = t >> 6;           // wave 0..15 = point group: 8 points
  const int p0   = wv * 8;
  const int blk  = blockIdx.x;
  const int b    = blk >> 3;         // 8 blocks per image
  const int hw0  = (blk & 7) * PTS;
  const float* inb = in + b * (D_ * HW) + hw0;

  // staging role: chunk-local code kl, dim-16-group h within the 32-d half
  const int kl = t & 511;
  const int h  = t >> 9;             // 0/1 (wave-uniform)
  // swizzled column of code kl: codes 8L+j -> col (j<4 ? L*4+j : 256+L*4+j-4)
  const int pos = ((kl >> 2) & 1) * 256 + (kl >> 3) * 4 + (kl & 3);

  // ---- stage x tile -> xT[d][p] (coalesced float4) ----
#pragma unroll
  for (int i = 0; i < 2; ++i) {
    int fi = t + i * 1024;                // 0..2047
    int d  = fi >> 5, p4 = fi & 31;
    *(float4*)(&xT[d * SP + p4 * 4]) = *(const float4*)(inb + d * HW + p4 * 4);
  }

  // ---- e2s: 1 code/thread, body identical to R4..R8 (rounding!) ----
  {
    const float4* e4 = (const float4*)(emb + t * 64);
    float s = 0.f;
#pragma unroll
    for (int q = 0; q < 16; ++q) {
      float4 v = e4[q];
      s += v.x * v.x; s += v.y * v.y; s += v.z * v.z; s += v.w * v.w;
    }
    e2s[t] = s;
  }

  // ---- stage (c=0, dh=0) into eTs ----
  {
    const float4* g = (const float4*)(emb + kl * 64 + h * 16);
    float4 v0 = g[0], v1 = g[1], v2 = g[2], v3 = g[3];
    int dq = h * 16;
    eTs[(dq + 0) * CK + pos] = v0.x; eTs[(dq + 1) * CK + pos] = v0.y;
    eTs[(dq + 2) * CK + pos] = v0.z; eTs[(dq + 3) * CK + pos] = v0.w;
    eTs[(dq + 4) * CK + pos] = v1.x; eTs[(dq + 5) * CK + pos] = v1.y;
    eTs[(dq + 6) * CK + pos] = v1.z; eTs[(dq + 7) * CK + pos] = v1.w;
    eTs[(dq + 8) * CK + pos] = v2.x; eTs[(dq + 9) * CK + pos] = v2.y;
    eTs[(dq +10) * CK + pos] = v2.z; eTs[(dq +11) * CK + pos] = v2.w;
    eTs[(dq +12) * CK + pos] = v3.x; eTs[(dq +13) * CK + pos] = v3.y;
    eTs[(dq +14) * CK + pos] = v3.z; eTs[(dq +15) * CK + pos] = v3.w;
  }
  __syncthreads();

  // ---- x2[p] from xT (sequential d fmaf chain — identical values) ----
  if (t < PTS) {
    float s = 0.f;
#pragma unroll 8
    for (int d = 0; d < D_; ++d) { float xv = xT[d * SP + t]; s = fmaf(xv, xv, s); }
    x2s[t] = s;
  }
  __syncthreads();

  float minv[8]; int mini[8];
#pragma unroll
  for (int i = 0; i < 8; ++i) { minv[i] = 3.4e38f; mini[i] = 0; }

  // ---- K loop: 2 chunks of 512 codes, each in two 32-d stages ----
#pragma unroll 1
  for (int c = 0; c < 2; ++c) {
    float acc[8][8];
#pragma unroll
    for (int i = 0; i < 8; ++i)
#pragma unroll
      for (int j = 0; j < 8; ++j) acc[i][j] = 0.f;

#pragma unroll 1
    for (int dh = 0; dh < 2; ++dh) {
      const int s = c * 2 + dh;

      const float* ep = &eTs[lane * 4];          // lane-contiguous: conflict-free
      const float* xp = &xT[dh * DH * SP + p0];  // wave-uniform broadcast
#pragma unroll 2
      for (int dd = 0; dd < DH; ++dd) {
        float4 e0 = *(const float4*)(ep);          // codes lane*8+0..3
        float4 e1 = *(const float4*)(ep + 256);    // codes lane*8+4..7
        float4 xa = *(const float4*)(xp);
        float4 xb = *(const float4*)(xp + 4);
        ep += CK; xp += SP;
        float xf[8] = {xa.x, xa.y, xa.z, xa.w, xb.x, xb.y, xb.z, xb.w};
        float ef[8] = {e0.x, e0.y, e0.z, e0.w, e1.x, e1.y, e1.z, e1.w};
#pragma unroll
        for (int i = 0; i < 8; ++i)
#pragma unroll
          for (int j = 0; j < 8; ++j)
            acc[i][j] = fmaf(xf[i], ef[j], acc[i][j]);
      }

      if (s < 3) {
        __syncthreads();   // all waves done reading this eTs stage
        // stage next (cn, dn) directly global->LDS (no regs held across
        // compute; ~700 cyc exposed per stage boundary, 3 total)
        const int cn = (s + 1) >> 1, dn = (s + 1) & 1;
        const float4* g =
            (const float4*)(emb + (cn * CK + kl) * 64 + dn * DH + h * 16);
        float4 v0 = g[0], v1 = g[1], v2 = g[2], v3 = g[3];
        int dq = h * 16;
        eTs[(dq + 0) * CK + pos] = v0.x; eTs[(dq + 1) * CK + pos] = v0.y;
        eTs[(dq + 2) * CK + pos] = v0.z; eTs[(dq + 3) * CK + pos] = v0.w;
        eTs[(dq + 4) * CK + pos] = v1.x; eTs[(dq + 5) * CK + pos] = v1.y;
        eTs[(dq + 6) * CK + pos] = v1.z; eTs[(dq + 7) * CK + pos] = v1.w;
        eTs[(dq + 8) * CK + pos] = v2.x; eTs[(dq + 9) * CK + pos] = v2.y;
        eTs[(dq +10) * CK + pos] = v2.z; eTs[(dq +11) * CK + pos] = v2.w;
        eTs[(dq +12) * CK + pos] = v3.x; eTs[(dq +13) * CK + pos] = v3.y;
        eTs[(dq +14) * CK + pos] = v3.z; eTs[(dq +15) * CK + pos] = v3.w;
        __syncthreads();
      }
    }

    // fold: u = fl(fl(x2 - 2*dot) + e2) — identical expression/order
    float x2v[8];
    {
      float4 xa = *(const float4*)&x2s[p0];      // broadcast
      float4 xb = *(const float4*)&x2s[p0 + 4];
      x2v[0]=xa.x; x2v[1]=xa.y; x2v[2]=xa.z; x2v[3]=xa.w;
      x2v[4]=xb.x; x2v[5]=xb.y; x2v[6]=xb.z; x2v[7]=xb.w;
    }
    float e2f[8];
    {
      const float4* p4 = (const float4*)&e2s[c * CK + lane * 8];
      float4 v0 = p4[0], v1 = p4[1];
      e2f[0]=v0.x; e2f[1]=v0.y; e2f[2]=v0.z; e2f[3]=v0.w;
      e2f[4]=v1.x; e2f[5]=v1.y; e2f[6]=v1.z; e2f[7]=v1.w;
    }
#pragma unroll
    for (int j = 0; j < 8; ++j) {
      int cg = c * CK + lane * 8 + j;            // ascending within thread
      float e2v = e2f[j];
#pragma unroll
      for (int i = 0; i < 8; ++i) {
        float u = fmaf(-2.f, acc[i][j], x2v[i]) + e2v;
        if (u < minv[i]) { minv[i] = u; mini[i] = cg; }
      }
    }
  }

  // ---- argmin: full-wave butterfly (each wave owns its 8 points) ----
#pragma unroll
  for (int i = 0; i < 8; ++i) {
    float v = minv[i]; int ix = mini[i];
#pragma unroll
    for (int off = 1; off < 64; off <<= 1) {
      float vo = __shfl_xor(v, off);
      int   io = __shfl_xor(ix, off);
      if (vo < v || (vo == v && io < ix)) { v = vo; ix = io; }  // tie -> lower
    }
    if (lane == 0) idx_sel[p0 + i] = ix;
  }
  __syncthreads();

  if (t < PTS) out[IDX_OFF + blk * PTS + t] = (float)idx_sel[t];

  // ---- fused epilogue: gather codes, loss partial, store quantized ----
  // t<512 with R4's EXACT per-thread partition/order -> loss bits identical.
  // x read from xT (bitwise copy of inb) -> same values as global reads.
  float* outq = out + 1 + b * (D_ * HW) + hw0;
  float lp = 0.f;
  if (t < 512) {
#pragma unroll
    for (int i = 0; i < 4; ++i) {
      int fi = t + i * 512;               // 0..2047
      int p = fi & 127, qd = fi >> 7;     // p contiguous per wave
      int cidx = idx_sel[p];
      float4 q = *(const float4*)(emb + cidx * 64 + qd * 4);
      float xv0 = xT[(qd * 4 + 0) * SP + p];
      float xv1 = xT[(qd * 4 + 1) * SP + p];
      float xv2 = xT[(qd * 4 + 2) * SP + p];
      float xv3 = xT[(qd * 4 + 3) * SP + p];
      float d0 = q.x - xv0, d1 = q.y - xv1, d2 = q.z - xv2, d3 = q.w - xv3;
      lp = fmaf(d0, d0, lp); lp = fmaf(d1, d1, lp);
      lp = fmaf(d2, d2, lp); lp = fmaf(d3, d3, lp);
      outq[(qd * 4 + 0) * HW + p] = xv0 + d0;
      outq[(qd * 4 + 1) * HW + p] = xv1 + d1;
      outq[(qd * 4 + 2) * HW + p] = xv2 + d2;
      outq[(qd * 4 + 3) * HW + p] = xv3 + d3;
    }

    // loss: wave -> block partials in R4's exact order (waves 0..7)
#pragma unroll
    for (int off = 1; off < 64; off <<= 1) lp += __shfl_xor(lp, off);
    if ((t & 63) == 0) redbuf[t >> 6] = lp;
  }
  __syncthreads();
  if (t == 0) {
    float part = 0.f;
#pragma unroll
    for (int w = 0; w < 8; ++w) part += redbuf[w];
    atomicAdd(loss_acc, part);
    __threadfence();
    unsigned old = atomicAdd(cnt, 1u);
    if (old == 255u) {
      __threadfence();
      float total = atomicAdd(loss_acc, 0.0f);  // coherent read-back
      float m = total * (1.0f / 2097152.0f);
      out[0] = m + 0.25f * m;                   // ref op order
    }
  }
}

extern "C" void kernel_launch(void* const* d_in, const int* in_sizes, int n_in,
                              void* d_out, int out_size, void* d_ws, size_t ws_size,
                              hipStream_t stream) {
  const float* in  = (const float*)d_in[0];
  const float* emb = (const float*)d_in[1];
  float* out = (float*)d_out;
  float* loss_acc = (float*)d_ws;                 // ws[0]
  unsigned* cnt   = (unsigned*)d_ws + 4;          // ws[4]

  hipMemsetAsync(d_ws, 0, 64, stream);            // zero accumulator + counter
  vq_main_kernel<<<256, 1024, 0, stream>>>(in, emb, out, loss_acc, cnt);
}